// Round 6
// baseline (786.485 us; speedup 1.0000x reference)
//
#include <hip/hip_runtime.h>
#include <cmath>

#define BB 16
#define CC 128
#define HH 128
#define WW 128
#define NN 1024
#define SS 256
#define BN (BB*NN)
#define K1 192            // first-layer K padded: 130 -> 192 (3 x 64)

typedef short short8v __attribute__((ext_vector_type(8)));
typedef float f32x4 __attribute__((ext_vector_type(4)));
typedef unsigned short u16;

__device__ __forceinline__ u16 f2bf(float f) {
    unsigned u = __builtin_bit_cast(unsigned, f);
    unsigned r = (u + 0x7FFFu + ((u >> 16) & 1u)) >> 16;
    return (u16)r;
}
__device__ __forceinline__ float bf2f(u16 h) {
    unsigned u = ((unsigned)h) << 16;
    return __builtin_bit_cast(float, u);
}

// ---------------------------------------------------------------------------
// casts
// ---------------------------------------------------------------------------
__global__ void k_cast4(const float* __restrict__ s, u16* __restrict__ d, long n4) {
    long i = (long)blockIdx.x * blockDim.x + threadIdx.x;
    long st = (long)gridDim.x * blockDim.x;
    for (; i < n4; i += st) {
        float4 v = ((const float4*)s)[i];
        ushort4 o;
        o.x = f2bf(v.x); o.y = f2bf(v.y); o.z = f2bf(v.z); o.w = f2bf(v.w);
        ((ushort4*)d)[i] = o;
    }
}

// first_W [2][256][130] -> bf16 [2][256][192] zero-padded
__global__ void k_castW1(const float* __restrict__ s, u16* __restrict__ d) {
    int idx = blockIdx.x * blockDim.x + threadIdx.x;
    if (idx >= 2 * 256 * K1) return;
    int k = idx % K1, r = idx / K1;
    d[idx] = (k < 130) ? f2bf(s[r * 130 + k]) : (u16)0;
}

// ---------------------------------------------------------------------------
// features [16][128][16384] f32 -> featT [16][16384][128] bf16 (tiled transpose)
// grid (16384/128, 16), block 256
// ---------------------------------------------------------------------------
__global__ __launch_bounds__(256) void k_ftrans(const float* __restrict__ f,
                                                u16* __restrict__ ft) {
    __shared__ u16 T[128][132];
    int b = blockIdx.y, hw0 = blockIdx.x * 128;
    int t = threadIdx.x;
    const float* fb = f + (long)b * CC * (HH * WW);
    #pragma unroll
    for (int p = 0; p < 16; ++p) {           // 8 c-rows per pass
        int c = p * 8 + (t >> 5);
        int x = (t & 31) * 4;
        float4 v = *(const float4*)(fb + (long)c * (HH * WW) + hw0 + x);
        T[x + 0][c] = f2bf(v.x); T[x + 1][c] = f2bf(v.y);
        T[x + 2][c] = f2bf(v.z); T[x + 3][c] = f2bf(v.w);
    }
    __syncthreads();
    #pragma unroll
    for (int p = 0; p < 8; ++p) {            // 16 hw-rows per pass
        int hw = p * 16 + (t >> 4);
        int c8 = (t & 15) * 8;
        short8v v = *(const short8v*)&T[hw][c8];
        *(short8v*)(ft + ((long)b * 16384 + hw0 + hw) * 128 + c8) = v;
    }
}

// ---------------------------------------------------------------------------
// interp: wave per node; lane = (corner<<4)|chunk. featT rows are 256B.
// writes Xh [BN][192] (cols 128/129 = px,py ; 130..191 = 0)
// ---------------------------------------------------------------------------
__global__ __launch_bounds__(256) void k_interp(const u16* __restrict__ featT,
                                                const float* __restrict__ base_point,
                                                u16* __restrict__ Xh) {
    int t = threadIdx.x;
    int lane = t & 63, w = t >> 6;
    int bn = blockIdx.x * 4 + w;
    int b = bn >> 10;
    float px = base_point[bn * 2 + 0];
    float py = base_point[bn * 2 + 1];
    float Xs = px * WW, Ys = py * HH;
    float X0f = floorf(Xs), Y0f = floorf(Ys);
    float fx = Xs - X0f, fy = Ys - Y0f;
    int x0 = min(max((int)X0f, 0), WW - 1);
    int x1 = min(max((int)(X0f + 1.f), 0), WW - 1);
    int y0 = min(max((int)Y0f, 0), HH - 1);
    int y1 = min(max((int)(Y0f + 1.f), 0), HH - 1);
    int corner = lane >> 4, chunk = lane & 15;
    int xi = (corner & 2) ? x1 : x0;
    int yi = (corner & 1) ? y1 : y0;
    float wgt = ((corner & 2) ? fx : 1.f - fx) * ((corner & 1) ? fy : 1.f - fy);
    const u16* fp = featT + ((long)b * 16384 + yi * WW + xi) * 128 + chunk * 8;
    short8v v = *(const short8v*)fp;
    float a[8];
    #pragma unroll
    for (int j = 0; j < 8; ++j) a[j] = wgt * bf2f((u16)v[j]);
    #pragma unroll
    for (int j = 0; j < 8; ++j) {
        a[j] += __shfl_xor(a[j], 16);
        a[j] += __shfl_xor(a[j], 32);
    }
    if (lane < 16) {
        short8v o;
        #pragma unroll
        for (int j = 0; j < 8; ++j) o[j] = (short)f2bf(a[j]);
        *(short8v*)(Xh + (long)bn * K1 + chunk * 8) = o;
    } else if (lane < 24) {
        short8v o = {};
        if (lane == 16) { o[0] = (short)f2bf(px); o[1] = (short)f2bf(py); }
        *(short8v*)(Xh + (long)bn * K1 + 128 + (lane - 16) * 8) = o;
    }
}

// ---------------------------------------------------------------------------
// Xh [16384][192] -> XhT [16][256][1024], rows 192..255 zeroed
// grid (1024/128, 16), block 256
// ---------------------------------------------------------------------------
__global__ __launch_bounds__(256) void k_xt(const u16* __restrict__ Xh,
                                            u16* __restrict__ XhT) {
    __shared__ u16 T[192][136];
    int b = blockIdx.y, n0 = blockIdx.x * 128;
    int t = threadIdx.x;
    #pragma unroll
    for (int p = 0; p < 12; ++p) {
        int idx = p * 256 + t;            // 3072 chunks = 128 nodes x 24
        int node = idx / 24, ch = idx % 24;
        short8v v = *(const short8v*)(Xh + ((long)(b * 1024 + n0 + node)) * K1 + ch * 8);
        #pragma unroll
        for (int j = 0; j < 8; ++j) T[ch * 8 + j][node] = (u16)v[j];
    }
    __syncthreads();
    #pragma unroll
    for (int p = 0; p < 12; ++p) {
        int c = p * 16 + (t >> 4);
        int m8 = (t & 15) * 8;
        short8v v = *(const short8v*)&T[c][m8];
        *(short8v*)(XhT + ((long)b * 256 + c) * 1024 + n0 + m8) = v;
    }
    #pragma unroll
    for (int p = 0; p < 4; ++p) {
        int c = 192 + p * 16 + (t >> 4);
        int m8 = (t & 15) * 8;
        short8v z = {};
        *(short8v*)(XhT + ((long)b * 256 + c) * 1024 + n0 + m8) = z;
    }
}

// ---------------------------------------------------------------------------
// MFMA GEMM: 8 waves (2M x 4N grid of 64x64), tile 128M x 256N (full N), BK=64.
// 3-stage 144 KB LDS pipeline, 2-deep prefetch, counted vmcnt(6), 1 barrier/step.
// C = [A0|A1] @ [B0|B1]^T (+bias +res, relu). B stored [n][K] k-contig, n=256.
// Stage layout per buffer: As 128x64 (16KB) @ +0, Bs 256x64 (32KB) @ +8192 u16.
// ---------------------------------------------------------------------------
__global__ __launch_bounds__(512) void k_mm(
    const u16* __restrict__ A0, int lda0, int nK0,
    const u16* __restrict__ A1, int lda1, int nK1,
    const u16* __restrict__ B0, int ldb0,
    const u16* __restrict__ B1, int ldb1,
    const float* __restrict__ bias0, const float* __restrict__ bias1,
    const u16* __restrict__ res, int do_relu,
    u16* __restrict__ outN, int ldoN,
    u16* __restrict__ outT,
    int batched, long sA, long sB, long sC) {

    __shared__ u16 lds[73728];               // 144 KB: 3 x (As 16KB + Bs 32KB)

    int t = threadIdx.x;
    int lane = t & 63, w = t >> 6;           // 8 waves
    int wr = w >> 2, wc = w & 3;             // 2x4 waves of 64x64
    long row0 = (long)blockIdx.y * 128;
    const u16* Ab0 = A0;
    const u16* Bb0 = B0;
    u16* oN = outN;
    if (batched) {
        int b = blockIdx.z;
        Ab0 += (long)b * sA;
        Bb0 += (long)b * sB;
        oN  += (long)b * sC;
    }

    int tot = nK0 + nK1;
    f32x4 acc[4][4] = {};

    auto stage = [&](int s, int bufbase) {   // 6 global_load_lds per thread
        const u16* Ap; int lda; const u16* Bp; int ldb; int kt;
        if (s < nK0) { Ap = Ab0; lda = lda0; Bp = Bb0; ldb = ldb0; kt = s * 64; }
        else         { Ap = A1;  lda = lda1; Bp = B1;  ldb = ldb1; kt = (s - nK0) * 64; }
        u16* As = lds + bufbase;
        u16* Bs = lds + bufbase + 8192;
        int rbase = t >> 3;                  // 0..63
        int slot  = t & 7;
        #pragma unroll
        for (int q = 0; q < 2; ++q) {        // A: 128 rows
            int r = q * 64 + rbase;
            int koff = kt + ((slot ^ (r & 7)) << 3);
            __builtin_amdgcn_global_load_lds(
                (const __attribute__((address_space(1))) void*)(Ap + (row0 + r) * lda + koff),
                (__attribute__((address_space(3))) void*)(As + r * 64 + slot * 8), 16, 0, 0);
        }
        #pragma unroll
        for (int q = 0; q < 4; ++q) {        // B: 256 rows
            int r = q * 64 + rbase;
            int koff = kt + ((slot ^ (r & 7)) << 3);
            __builtin_amdgcn_global_load_lds(
                (const __attribute__((address_space(1))) void*)(Bp + (long)r * ldb + koff),
                (__attribute__((address_space(3))) void*)(Bs + r * 64 + slot * 8), 16, 0, 0);
        }
    };

    stage(0, 0);
    if (tot > 1) stage(1, 24576);

    int curb = 0, stb = 49152;
    for (int s = 0; s < tot; ++s) {
        if (s + 1 < tot) { asm volatile("s_waitcnt vmcnt(6)" ::: "memory"); }
        else             { asm volatile("s_waitcnt vmcnt(0)" ::: "memory"); }
        __builtin_amdgcn_sched_barrier(0);
        __builtin_amdgcn_s_barrier();        // buffer landed + prev reads done
        if (s + 2 < tot) stage(s + 2, stb);  // overwrites buffer read 1 iter ago
        const u16* As = lds + curb;
        const u16* Bs = lds + curb + 8192;
        #pragma unroll
        for (int kk = 0; kk < 2; ++kk) {
            short8v a[4], bfr[4];
            #pragma unroll
            for (int m = 0; m < 4; ++m) {
                int row = wr * 64 + m * 16 + (lane & 15);
                int sl = (kk * 4 + (lane >> 4)) ^ (row & 7);
                a[m] = *(const short8v*)(As + row * 64 + sl * 8);
            }
            #pragma unroll
            for (int n = 0; n < 4; ++n) {
                int row = wc * 64 + n * 16 + (lane & 15);
                int sl = (kk * 4 + (lane >> 4)) ^ (row & 7);
                bfr[n] = *(const short8v*)(Bs + row * 64 + sl * 8);
            }
            #pragma unroll
            for (int m = 0; m < 4; ++m)
                #pragma unroll
                for (int n = 0; n < 4; ++n)
                    acc[m][n] = __builtin_amdgcn_mfma_f32_16x16x32_bf16(
                        a[m], bfr[n], acc[m][n], 0, 0, 0);
        }
        curb += 24576; if (curb == 73728) curb = 0;
        stb  += 24576; if (stb  == 73728) stb  = 0;
    }

    // ---- epilogue ----
    int mbase = wr * 64, nbase = wc * 64;
    u16 vals[4][4][4];
    #pragma unroll
    for (int m = 0; m < 4; ++m)
        #pragma unroll
        for (int n = 0; n < 4; ++n)
            #pragma unroll
            for (int r = 0; r < 4; ++r) {
                int rr = mbase + m * 16 + (lane >> 4) * 4 + r;
                int cc = nbase + n * 16 + (lane & 15);
                long grow = row0 + rr;
                int gcol = cc;
                float v = acc[m][n][r];
                if (bias0) v += bias0[gcol] + bias1[gcol];
                if (res)   v += bf2f(res[grow * ldoN + gcol]);
                if (do_relu) v = fmaxf(v, 0.f);
                u16 hv = f2bf(v);
                oN[grow * ldoN + gcol] = hv;
                vals[m][n][r] = hv;
            }

    if (outT) {
        u16 (*T)[136] = (u16(*)[136])lds;     // 256 x 136 = 69.6 KB
        __syncthreads();
        #pragma unroll
        for (int m = 0; m < 4; ++m)
            #pragma unroll
            for (int n = 0; n < 4; ++n)
                #pragma unroll
                for (int r = 0; r < 4; ++r) {
                    int rr = mbase + m * 16 + (lane >> 4) * 4 + r;
                    int cc = nbase + n * 16 + (lane & 15);
                    T[cc][rr] = vals[m][n][r];
                }
        __syncthreads();
        int bb2 = (int)(row0 >> 10);
        long nodeBase = row0 & 1023;
        #pragma unroll
        for (int p = 0; p < 8; ++p) {
            int c = p * 32 + (t >> 4);
            int moff = (t & 15) * 8;
            short8v vv = *(const short8v*)(&T[c][moff]);
            *(short8v*)(outT + ((long)bb2 * 256 + c) * 1024 + nodeBase + moff) = vv;
        }
    }
}

// ---------------------------------------------------------------------------
// FC head
// ---------------------------------------------------------------------------
__global__ void k_fc(const u16* __restrict__ Hf,
                     const float* __restrict__ fcW, const float* __restrict__ fcb,
                     const float* __restrict__ base_point,
                     const float* __restrict__ mask,
                     float* __restrict__ out, float* __restrict__ G) {
    int bn = blockIdx.x * blockDim.x + threadIdx.x;
    if (bn >= BN) return;
    const u16* hr = Hf + (long)bn * SS;
    float a0 = fcb[0], a1 = fcb[1];
    for (int k = 0; k < SS; k += 8) {
        short8v v = *(const short8v*)(hr + k);
        #pragma unroll
        for (int j = 0; j < 8; ++j) {
            float f = bf2f((u16)v[j]);
            a0 += f * fcW[k + j];
            a1 += f * fcW[SS + k + j];
        }
    }
    float m  = mask[bn];
    float p0 = base_point[bn * 2 + 0], p1 = base_point[bn * 2 + 1];
    float g0 = a0 * m, g1 = a1 * m;
    out[16 + bn * 2 + 0] = p0 + g0;
    out[16 + bn * 2 + 1] = p1 + g1;
    out[16 + BN * 2 + bn * 2 + 0] = a0;
    out[16 + BN * 2 + bn * 2 + 1] = a1;
    G[bn * 2 + 0] = g0;
    G[bn * 2 + 1] = g1;
}

// ---------------------------------------------------------------------------
// AG = adj @ G (fp32 G, bf16 adj); one wave per output row
// ---------------------------------------------------------------------------
__global__ __launch_bounds__(256) void k_adjg(const u16* __restrict__ adjh,
                                              const float* __restrict__ G,
                                              float* __restrict__ AG) {
    int w = threadIdx.x >> 6, lane = threadIdx.x & 63;
    long row = (long)blockIdx.x * 4 + w;
    int b = (int)(row >> 10);
    const u16* ar = adjh + ((long)b * NN + (row & 1023)) * NN;
    const float* Gb = G + (long)b * NN * 2;
    float s0 = 0.f, s1 = 0.f;
    int k0 = lane * 16;
    #pragma unroll
    for (int q = 0; q < 2; ++q) {
        short8v av = *(const short8v*)(ar + k0 + q * 8);
        #pragma unroll
        for (int j = 0; j < 8; ++j) {
            float a = bf2f((u16)av[j]);
            int k = k0 + q * 8 + j;
            s0 += a * Gb[k * 2 + 0];
            s1 += a * Gb[k * 2 + 1];
        }
    }
    #pragma unroll
    for (int off = 32; off; off >>= 1) {
        s0 += __shfl_down(s0, off);
        s1 += __shfl_down(s1, off);
    }
    if (lane == 0) { AG[row * 2 + 0] = s0; AG[row * 2 + 1] = s1; }
}

// ---------------------------------------------------------------------------
// energy
// ---------------------------------------------------------------------------
__global__ __launch_bounds__(256) void k_energy(const float* __restrict__ G,
                                                const float* __restrict__ AG,
                                                float* __restrict__ out) {
    __shared__ float red[256];
    int b = blockIdx.x, t = threadIdx.x;
    float s = 0.f;
    for (int n = t; n < NN; n += 256) {
        int bn = b * NN + n;
        float dx = G[bn * 2 + 0] - AG[bn * 2 + 0];
        float dy = G[bn * 2 + 1] - AG[bn * 2 + 1];
        s += sqrtf(dx * dx + dy * dy + 1e-10f);
    }
    red[t] = s;
    __syncthreads();
    for (int off = 128; off > 0; off >>= 1) {
        if (t < off) red[t] += red[t + off];
        __syncthreads();
    }
    if (t == 0) out[b] = red[0] / (float)NN;
}

// ---------------------------------------------------------------------------
extern "C" void kernel_launch(void* const* d_in, const int* in_sizes, int n_in,
                              void* d_out, int out_size, void* d_ws, size_t ws_size,
                              hipStream_t stream) {
    const float* features   = (const float*)d_in[0];
    const float* base_point = (const float*)d_in[1];
    const float* adj        = (const float*)d_in[2];
    const float* mask       = (const float*)d_in[3];
    const float* first_W    = (const float*)d_in[4];
    const float* first_b    = (const float*)d_in[5];
    const float* mid_W      = (const float*)d_in[6];
    const float* mid_b      = (const float*)d_in[7];
    const float* last_W     = (const float*)d_in[8];
    const float* last_b     = (const float*)d_in[9];
    const float* fc_W       = (const float*)d_in[10];
    const float* fc_b       = (const float*)d_in[11];
    float* out = (float*)d_out;
    char* p = (char*)d_ws;

    // Region 0 (67.1 MB): featT lives here first; after interp it is dead and
    // the region is reused for adjh / AGG / Hn / On / G / AG.
    u16*  featT = (u16*)p;
    u16*  adjh  = (u16*)p;                                   // 33.55 MB
    u16*  AGG   = (u16*)(p + 33554432);                      //  8.39 MB
    u16*  Hn    = (u16*)(p + 33554432 + 8388608);            //  8.39 MB
    u16*  On    = (u16*)(p + 33554432 + 2 * 8388608);        //  8.39 MB
    float* G    = (float*)(p + 33554432 + 3 * 8388608);      //  0.13 MB
    float* AG   = G + (size_t)BN * 2;                        //  0.13 MB
    p += (size_t)BB * 16384 * 128 * 2;                       // 67108864

    u16* Xh  = (u16*)p;  p += (size_t)BN * K1 * 2;
    u16* XhT = (u16*)p;  p += (size_t)BB * 256 * 1024 * 2;
    u16* HnT = (u16*)p;  p += (size_t)BB * 256 * 1024 * 2;
    u16* OnT = (u16*)p;  p += (size_t)BB * 256 * 1024 * 2;
    u16* Whf = (u16*)p;  p += (size_t)2 * 256 * K1 * 2;
    u16* Whm = (u16*)p;  p += (size_t)6 * 4 * 256 * 256 * 2;
    u16* Whl = (u16*)p;  p += (size_t)2 * 256 * 256 * 2;

    // interp path first (featT region), then overwrite region with adjh etc.
    k_ftrans<<<dim3(128, 16), 256, 0, stream>>>(features, featT);
    k_interp<<<BN / 4, 256, 0, stream>>>(featT, base_point, Xh);
    k_xt<<<dim3(8, 16), 256, 0, stream>>>(Xh, XhT);

    k_cast4<<<2048, 256, 0, stream>>>(adj, adjh, (long)BB * NN * NN / 4);
    k_cast4<<<256, 256, 0, stream>>>(mid_W, Whm, (long)6 * 4 * 256 * 256 / 4);
    k_cast4<<<64, 256, 0, stream>>>(last_W, Whl, (long)2 * 256 * 256 / 4);
    k_castW1<<<(2 * 256 * K1 + 255) / 256, 256, 0, stream>>>(first_W, Whf);

    const long sA = (long)NN * NN, sB = 256L * 1024, sC = (long)NN * 256;
    dim3 gAgg(1, 8, 16), gGc(1, 128, 1), blk(512);

    // first layer
    k_mm<<<gAgg, blk, 0, stream>>>(adjh, NN, 16, nullptr, 0, 0, XhT, NN, nullptr, 0,
                                   nullptr, nullptr, nullptr, 0,
                                   AGG, 256, nullptr, 1, sA, sB, sC);
    k_mm<<<gGc, blk, 0, stream>>>(Xh, K1, 3, AGG, 256, 3, Whf, K1, Whf + 256 * K1, K1,
                                  first_b, first_b + 256, nullptr, 1,
                                  Hn, 256, HnT, 0, 0, 0, 0);

    for (int i = 0; i < 6; ++i) {
        const u16* W = Whm + (size_t)i * 4 * 256 * 256;
        const float* bb = mid_b + (size_t)i * 4 * 256;
        k_mm<<<gAgg, blk, 0, stream>>>(adjh, NN, 16, nullptr, 0, 0, HnT, NN, nullptr, 0,
                                       nullptr, nullptr, nullptr, 0,
                                       AGG, 256, nullptr, 1, sA, sB, sC);
        k_mm<<<gGc, blk, 0, stream>>>(Hn, 256, 4, AGG, 256, 4, W, 256, W + 65536, 256,
                                      bb, bb + 256, nullptr, 1,
                                      On, 256, OnT, 0, 0, 0, 0);
        k_mm<<<gAgg, blk, 0, stream>>>(adjh, NN, 16, nullptr, 0, 0, OnT, NN, nullptr, 0,
                                       nullptr, nullptr, nullptr, 0,
                                       AGG, 256, nullptr, 1, sA, sB, sC);
        k_mm<<<gGc, blk, 0, stream>>>(On, 256, 4, AGG, 256, 4,
                                      W + 2 * 65536, 256, W + 3 * 65536, 256,
                                      bb + 512, bb + 768, Hn, 1,
                                      Hn, 256, HnT, 0, 0, 0, 0);
    }

    // last layer
    k_mm<<<gAgg, blk, 0, stream>>>(adjh, NN, 16, nullptr, 0, 0, HnT, NN, nullptr, 0,
                                   nullptr, nullptr, nullptr, 0,
                                   AGG, 256, nullptr, 1, sA, sB, sC);
    k_mm<<<gGc, blk, 0, stream>>>(Hn, 256, 4, AGG, 256, 4, Whl, 256, Whl + 65536, 256,
                                  last_b, last_b + 256, nullptr, 1,
                                  On, 256, nullptr, 0, 0, 0, 0);

    // head + energy
    k_fc<<<BN / 256, 256, 0, stream>>>(On, fc_W, fc_b, base_point, mask, out, G);
    k_adjg<<<BN / 4, 256, 0, stream>>>(adjh, G, AG);
    k_energy<<<BB, 256, 0, stream>>>(G, AG, out);
}

// Round 7
// 700.827 us; speedup vs baseline: 1.1222x; 1.1222x over previous
//
#include <hip/hip_runtime.h>
#include <cmath>

#define BB 16
#define CC 128
#define HH 128
#define WW 128
#define NN 1024
#define SS 256
#define BN (BB*NN)
#define K1 192            // first-layer K padded: 130 -> 192 (3 x 64)

typedef short short8v __attribute__((ext_vector_type(8)));
typedef float f32x4 __attribute__((ext_vector_type(4)));
typedef unsigned short u16;

__device__ __forceinline__ u16 f2bf(float f) {
    unsigned u = __builtin_bit_cast(unsigned, f);
    unsigned r = (u + 0x7FFFu + ((u >> 16) & 1u)) >> 16;
    return (u16)r;
}
__device__ __forceinline__ float bf2f(u16 h) {
    unsigned u = ((unsigned)h) << 16;
    return __builtin_bit_cast(float, u);
}

// ---------------------------------------------------------------------------
// casts
// ---------------------------------------------------------------------------
__global__ void k_cast4(const float* __restrict__ s, u16* __restrict__ d, long n4) {
    long i = (long)blockIdx.x * blockDim.x + threadIdx.x;
    long st = (long)gridDim.x * blockDim.x;
    for (; i < n4; i += st) {
        float4 v = ((const float4*)s)[i];
        ushort4 o;
        o.x = f2bf(v.x); o.y = f2bf(v.y); o.z = f2bf(v.z); o.w = f2bf(v.w);
        ((ushort4*)d)[i] = o;
    }
}

// first_W [2][256][130] -> bf16 [2][256][192] zero-padded
__global__ void k_castW1(const float* __restrict__ s, u16* __restrict__ d) {
    int idx = blockIdx.x * blockDim.x + threadIdx.x;
    if (idx >= 2 * 256 * K1) return;
    int k = idx % K1, r = idx / K1;
    d[idx] = (k < 130) ? f2bf(s[r * 130 + k]) : (u16)0;
}

// ---------------------------------------------------------------------------
// features [16][128][16384] f32 -> featT [16][16384][128] bf16 (tiled transpose)
// ---------------------------------------------------------------------------
__global__ __launch_bounds__(256) void k_ftrans(const float* __restrict__ f,
                                                u16* __restrict__ ft) {
    __shared__ u16 T[128][132];
    int b = blockIdx.y, hw0 = blockIdx.x * 128;
    int t = threadIdx.x;
    const float* fb = f + (long)b * CC * (HH * WW);
    #pragma unroll
    for (int p = 0; p < 16; ++p) {
        int c = p * 8 + (t >> 5);
        int x = (t & 31) * 4;
        float4 v = *(const float4*)(fb + (long)c * (HH * WW) + hw0 + x);
        T[x + 0][c] = f2bf(v.x); T[x + 1][c] = f2bf(v.y);
        T[x + 2][c] = f2bf(v.z); T[x + 3][c] = f2bf(v.w);
    }
    __syncthreads();
    #pragma unroll
    for (int p = 0; p < 8; ++p) {
        int hw = p * 16 + (t >> 4);
        int c8 = (t & 15) * 8;
        short8v v = *(const short8v*)&T[hw][c8];
        *(short8v*)(ft + ((long)b * 16384 + hw0 + hw) * 128 + c8) = v;
    }
}

// ---------------------------------------------------------------------------
// interp: wave per node; lane = (corner<<4)|chunk.
// ---------------------------------------------------------------------------
__global__ __launch_bounds__(256) void k_interp(const u16* __restrict__ featT,
                                                const float* __restrict__ base_point,
                                                u16* __restrict__ Xh) {
    int t = threadIdx.x;
    int lane = t & 63, w = t >> 6;
    int bn = blockIdx.x * 4 + w;
    int b = bn >> 10;
    float px = base_point[bn * 2 + 0];
    float py = base_point[bn * 2 + 1];
    float Xs = px * WW, Ys = py * HH;
    float X0f = floorf(Xs), Y0f = floorf(Ys);
    float fx = Xs - X0f, fy = Ys - Y0f;
    int x0 = min(max((int)X0f, 0), WW - 1);
    int x1 = min(max((int)(X0f + 1.f), 0), WW - 1);
    int y0 = min(max((int)Y0f, 0), HH - 1);
    int y1 = min(max((int)(Y0f + 1.f), 0), HH - 1);
    int corner = lane >> 4, chunk = lane & 15;
    int xi = (corner & 2) ? x1 : x0;
    int yi = (corner & 1) ? y1 : y0;
    float wgt = ((corner & 2) ? fx : 1.f - fx) * ((corner & 1) ? fy : 1.f - fy);
    const u16* fp = featT + ((long)b * 16384 + yi * WW + xi) * 128 + chunk * 8;
    short8v v = *(const short8v*)fp;
    float a[8];
    #pragma unroll
    for (int j = 0; j < 8; ++j) a[j] = wgt * bf2f((u16)v[j]);
    #pragma unroll
    for (int j = 0; j < 8; ++j) {
        a[j] += __shfl_xor(a[j], 16);
        a[j] += __shfl_xor(a[j], 32);
    }
    if (lane < 16) {
        short8v o;
        #pragma unroll
        for (int j = 0; j < 8; ++j) o[j] = (short)f2bf(a[j]);
        *(short8v*)(Xh + (long)bn * K1 + chunk * 8) = o;
    } else if (lane < 24) {
        short8v o = {};
        if (lane == 16) { o[0] = (short)f2bf(px); o[1] = (short)f2bf(py); }
        *(short8v*)(Xh + (long)bn * K1 + 128 + (lane - 16) * 8) = o;
    }
}

// ---------------------------------------------------------------------------
// Xh [16384][192] -> XhT [16][256][1024], rows 192..255 zeroed
// ---------------------------------------------------------------------------
__global__ __launch_bounds__(256) void k_xt(const u16* __restrict__ Xh,
                                            u16* __restrict__ XhT) {
    __shared__ u16 T[192][136];
    int b = blockIdx.y, n0 = blockIdx.x * 128;
    int t = threadIdx.x;
    #pragma unroll
    for (int p = 0; p < 12; ++p) {
        int idx = p * 256 + t;
        int node = idx / 24, ch = idx % 24;
        short8v v = *(const short8v*)(Xh + ((long)(b * 1024 + n0 + node)) * K1 + ch * 8);
        #pragma unroll
        for (int j = 0; j < 8; ++j) T[ch * 8 + j][node] = (u16)v[j];
    }
    __syncthreads();
    #pragma unroll
    for (int p = 0; p < 12; ++p) {
        int c = p * 16 + (t >> 4);
        int m8 = (t & 15) * 8;
        short8v v = *(const short8v*)&T[c][m8];
        *(short8v*)(XhT + ((long)b * 256 + c) * 1024 + n0 + m8) = v;
    }
    #pragma unroll
    for (int p = 0; p < 4; ++p) {
        int c = 192 + p * 16 + (t >> 4);
        int m8 = (t & 15) * 8;
        short8v z = {};
        *(short8v*)(XhT + ((long)b * 256 + c) * 1024 + n0 + m8) = z;
    }
}

// ---------------------------------------------------------------------------
// MFMA GEMM, 8 waves, 128x128 tile, BK=64, 3-stage pipeline, vmcnt(4).
// K-SPLIT waves: 4 positions (2x2 of 64x64) x 2 K-halves; partials merged
// via 64KB LDS fp32 roundtrip in the epilogue.
// agg-mode (batched): XCD-aware block remap so batch z sticks to XCD z%8.
// ---------------------------------------------------------------------------
__global__ __launch_bounds__(512) void k_mm(
    const u16* __restrict__ A0, int lda0, int nK0,
    const u16* __restrict__ A1, int lda1, int nK1,
    const u16* __restrict__ B0, int ldb0,
    const u16* __restrict__ B1, int ldb1,
    const float* __restrict__ bias0, const float* __restrict__ bias1,
    const u16* __restrict__ res, int do_relu,
    u16* __restrict__ outN, int ldoN,
    u16* __restrict__ outT,
    int batched, long sA, long sB, long sC) {

    __shared__ u16 lds[49152];               // 96 KB: 3 x (As 16KB + Bs 16KB)

    int t = threadIdx.x;
    int lane = t & 63, w = t >> 6;           // 8 waves
    int pos = w & 3;                         // 2x2 positions of 64x64
    int wr = pos >> 1, wc = pos & 1;
    int kh = w >> 2;                         // K-half 0/1

    int bx = blockIdx.x, by = blockIdx.y, bz = blockIdx.z;
    if (batched) {                           // grid (2,8,16): pin batch to XCD
        int f = bx + 2 * by + 16 * bz;
        int zz = f & 15, tt = f >> 4;
        bx = tt & 1; by = tt >> 1; bz = zz;
    }
    int c0 = bx * 128;
    long row0 = (long)by * 128;
    const u16* Ab0 = A0;
    const u16* Bb0 = B0;
    u16* oN = outN;
    if (batched) {
        Ab0 += (long)bz * sA;
        Bb0 += (long)bz * sB;
        oN  += (long)bz * sC;
    }

    int tot = nK0 + nK1;
    f32x4 acc[4][4] = {};

    auto stage = [&](int s, int bufbase) {   // 4 global_load_lds per thread
        const u16* Ap; int lda; const u16* Bp; int ldb; int kt;
        if (s < nK0) { Ap = Ab0; lda = lda0; Bp = Bb0; ldb = ldb0; kt = s * 64; }
        else         { Ap = A1;  lda = lda1; Bp = B1;  ldb = ldb1; kt = (s - nK0) * 64; }
        u16* As = lds + bufbase;
        u16* Bs = lds + bufbase + 8192;
        #pragma unroll
        for (int q = 0; q < 2; ++q) {
            int rb = w * 16 + q * 8;
            int row = rb + (lane >> 3);
            int koff = kt + (((lane & 7) ^ (row & 7)) << 3);
            __builtin_amdgcn_global_load_lds(
                (const __attribute__((address_space(1))) void*)(Ap + (row0 + row) * lda + koff),
                (__attribute__((address_space(3))) void*)(As + row * 64 + (lane & 7) * 8), 16, 0, 0);
            __builtin_amdgcn_global_load_lds(
                (const __attribute__((address_space(1))) void*)(Bp + (long)(c0 + row) * ldb + koff),
                (__attribute__((address_space(3))) void*)(Bs + row * 64 + (lane & 7) * 8), 16, 0, 0);
        }
    };

    stage(0, 0);
    if (tot > 1) stage(1, 16384);

    int curb = 0, stb = 32768;
    for (int s = 0; s < tot; ++s) {
        if (s + 1 < tot) { asm volatile("s_waitcnt vmcnt(4)" ::: "memory"); }
        else             { asm volatile("s_waitcnt vmcnt(0)" ::: "memory"); }
        __builtin_amdgcn_sched_barrier(0);
        __builtin_amdgcn_s_barrier();        // buffer landed + prev reads done
        if (s + 2 < tot) stage(s + 2, stb);  // overwrites buffer read 1 iter ago
        const u16* As = lds + curb;
        const u16* Bs = lds + curb + 8192;
        short8v a[4], bfr[4];
        #pragma unroll
        for (int m = 0; m < 4; ++m) {
            int row = wr * 64 + m * 16 + (lane & 15);
            int sl = (kh * 4 + (lane >> 4)) ^ (row & 7);
            a[m] = *(const short8v*)(As + row * 64 + sl * 8);
        }
        #pragma unroll
        for (int n = 0; n < 4; ++n) {
            int row = wc * 64 + n * 16 + (lane & 15);
            int sl = (kh * 4 + (lane >> 4)) ^ (row & 7);
            bfr[n] = *(const short8v*)(Bs + row * 64 + sl * 8);
        }
        #pragma unroll
        for (int m = 0; m < 4; ++m)
            #pragma unroll
            for (int n = 0; n < 4; ++n)
                acc[m][n] = __builtin_amdgcn_mfma_f32_16x16x32_bf16(
                    a[m], bfr[n], acc[m][n], 0, 0, 0);
        curb += 16384; if (curb == 49152) curb = 0;
        stb  += 16384; if (stb  == 49152) stb  = 0;
    }

    // ---- K-half reduction: kh1 dumps fp32 partials, kh0 merges ----
    __syncthreads();
    float* red = (float*)lds;                // 4 pos x 64x64 f32 = 64 KB
    if (kh == 1) {
        #pragma unroll
        for (int m = 0; m < 4; ++m)
            #pragma unroll
            for (int n = 0; n < 4; ++n)
                #pragma unroll
                for (int r = 0; r < 4; ++r) {
                    int rr = m * 16 + (lane >> 4) * 4 + r;
                    int cc = n * 16 + (lane & 15);
                    red[pos * 4096 + rr * 64 + cc] = acc[m][n][r];
                }
    }
    __syncthreads();

    int mbase = wr * 64, nbase = wc * 64;
    u16 vals[4][4][4];
    if (kh == 0) {
        #pragma unroll
        for (int m = 0; m < 4; ++m)
            #pragma unroll
            for (int n = 0; n < 4; ++n)
                #pragma unroll
                for (int r = 0; r < 4; ++r) {
                    int rr = m * 16 + (lane >> 4) * 4 + r;
                    int cc = n * 16 + (lane & 15);
                    long grow = row0 + mbase + rr;
                    int gcol = c0 + nbase + cc;
                    float v = acc[m][n][r] + red[pos * 4096 + rr * 64 + cc];
                    if (bias0) v += bias0[gcol] + bias1[gcol];
                    if (res)   v += bf2f(res[grow * ldoN + gcol]);
                    if (do_relu) v = fmaxf(v, 0.f);
                    u16 hv = f2bf(v);
                    oN[grow * ldoN + gcol] = hv;
                    vals[m][n][r] = hv;
                }
    }

    if (outT) {
        __syncthreads();                     // red fully consumed; reuse as T
        u16 (*T)[136] = (u16(*)[136])lds;    // 128 x 136 = 34.8 KB
        if (kh == 0) {
            #pragma unroll
            for (int m = 0; m < 4; ++m)
                #pragma unroll
                for (int n = 0; n < 4; ++n)
                    #pragma unroll
                    for (int r = 0; r < 4; ++r) {
                        int rr = mbase + m * 16 + (lane >> 4) * 4 + r;
                        int cc = nbase + n * 16 + (lane & 15);
                        T[cc][rr] = vals[m][n][r];
                    }
        }
        __syncthreads();
        int bb2 = (int)(row0 >> 10);
        long nodeBase = row0 & 1023;
        #pragma unroll
        for (int p = 0; p < 4; ++p) {
            int c = p * 32 + (t >> 4);
            int moff = (t & 15) * 8;
            short8v vv = *(const short8v*)(&T[c][moff]);
            *(short8v*)(outT + ((long)bb2 * 256 + c0 + c) * 1024 + nodeBase + moff) = vv;
        }
    }
}

// ---------------------------------------------------------------------------
// FC head: 8 lanes per node, shfl reduce. grid 512 x 256.
// ---------------------------------------------------------------------------
__global__ __launch_bounds__(256) void k_fc(const u16* __restrict__ Hf,
                     const float* __restrict__ fcW, const float* __restrict__ fcb,
                     const float* __restrict__ base_point,
                     const float* __restrict__ mask,
                     float* __restrict__ out, float* __restrict__ G) {
    int t = threadIdx.x;
    int w = t >> 6, l = t & 63;
    int bn = blockIdx.x * 32 + w * 8 + (l >> 3);
    int kc = (l & 7) * 32;
    const u16* hr = Hf + (long)bn * SS + kc;
    float a0 = 0.f, a1 = 0.f;
    #pragma unroll
    for (int j = 0; j < 32; j += 8) {
        short8v v = *(const short8v*)(hr + j);
        #pragma unroll
        for (int jj = 0; jj < 8; ++jj) {
            float f = bf2f((u16)v[jj]);
            a0 += f * fcW[kc + j + jj];
            a1 += f * fcW[SS + kc + j + jj];
        }
    }
    #pragma unroll
    for (int off = 1; off < 8; off <<= 1) {
        a0 += __shfl_xor(a0, off);
        a1 += __shfl_xor(a1, off);
    }
    if ((l & 7) == 0) {
        a0 += fcb[0]; a1 += fcb[1];
        float m  = mask[bn];
        float p0 = base_point[bn * 2 + 0], p1 = base_point[bn * 2 + 1];
        float g0 = a0 * m, g1 = a1 * m;
        out[16 + bn * 2 + 0] = p0 + g0;
        out[16 + bn * 2 + 1] = p1 + g1;
        out[16 + BN * 2 + bn * 2 + 0] = a0;
        out[16 + BN * 2 + bn * 2 + 1] = a1;
        G[bn * 2 + 0] = g0;
        G[bn * 2 + 1] = g1;
    }
}

// ---------------------------------------------------------------------------
// AG = adj @ G (fp32 G, bf16 adj); one wave per output row
// ---------------------------------------------------------------------------
__global__ __launch_bounds__(256) void k_adjg(const u16* __restrict__ adjh,
                                              const float* __restrict__ G,
                                              float* __restrict__ AG) {
    int w = threadIdx.x >> 6, lane = threadIdx.x & 63;
    long row = (long)blockIdx.x * 4 + w;
    int b = (int)(row >> 10);
    const u16* ar = adjh + ((long)b * NN + (row & 1023)) * NN;
    const float* Gb = G + (long)b * NN * 2;
    float s0 = 0.f, s1 = 0.f;
    int k0 = lane * 16;
    #pragma unroll
    for (int q = 0; q < 2; ++q) {
        short8v av = *(const short8v*)(ar + k0 + q * 8);
        #pragma unroll
        for (int j = 0; j < 8; ++j) {
            float a = bf2f((u16)av[j]);
            int k = k0 + q * 8 + j;
            s0 += a * Gb[k * 2 + 0];
            s1 += a * Gb[k * 2 + 1];
        }
    }
    #pragma unroll
    for (int off = 32; off; off >>= 1) {
        s0 += __shfl_down(s0, off);
        s1 += __shfl_down(s1, off);
    }
    if (lane == 0) { AG[row * 2 + 0] = s0; AG[row * 2 + 1] = s1; }
}

// ---------------------------------------------------------------------------
// energy
// ---------------------------------------------------------------------------
__global__ __launch_bounds__(256) void k_energy(const float* __restrict__ G,
                                                const float* __restrict__ AG,
                                                float* __restrict__ out) {
    __shared__ float red[256];
    int b = blockIdx.x, t = threadIdx.x;
    float s = 0.f;
    for (int n = t; n < NN; n += 256) {
        int bn = b * NN + n;
        float dx = G[bn * 2 + 0] - AG[bn * 2 + 0];
        float dy = G[bn * 2 + 1] - AG[bn * 2 + 1];
        s += sqrtf(dx * dx + dy * dy + 1e-10f);
    }
    red[t] = s;
    __syncthreads();
    for (int off = 128; off > 0; off >>= 1) {
        if (t < off) red[t] += red[t + off];
        __syncthreads();
    }
    if (t == 0) out[b] = red[0] / (float)NN;
}

// ---------------------------------------------------------------------------
extern "C" void kernel_launch(void* const* d_in, const int* in_sizes, int n_in,
                              void* d_out, int out_size, void* d_ws, size_t ws_size,
                              hipStream_t stream) {
    const float* features   = (const float*)d_in[0];
    const float* base_point = (const float*)d_in[1];
    const float* adj        = (const float*)d_in[2];
    const float* mask       = (const float*)d_in[3];
    const float* first_W    = (const float*)d_in[4];
    const float* first_b    = (const float*)d_in[5];
    const float* mid_W      = (const float*)d_in[6];
    const float* mid_b      = (const float*)d_in[7];
    const float* last_W     = (const float*)d_in[8];
    const float* last_b     = (const float*)d_in[9];
    const float* fc_W       = (const float*)d_in[10];
    const float* fc_b       = (const float*)d_in[11];
    float* out = (float*)d_out;
    char* p = (char*)d_ws;

    // Region 0 (67.1 MB): featT first; then reused for adjh / AGG / Hn / On / G / AG.
    u16*  featT = (u16*)p;
    u16*  adjh  = (u16*)p;                                   // 33.55 MB
    u16*  AGG   = (u16*)(p + 33554432);                      //  8.39 MB
    u16*  Hn    = (u16*)(p + 33554432 + 8388608);            //  8.39 MB
    u16*  On    = (u16*)(p + 33554432 + 2 * 8388608);        //  8.39 MB
    float* G    = (float*)(p + 33554432 + 3 * 8388608);      //  0.13 MB
    float* AG   = G + (size_t)BN * 2;                        //  0.13 MB
    p += (size_t)BB * 16384 * 128 * 2;                       // 67108864

    u16* Xh  = (u16*)p;  p += (size_t)BN * K1 * 2;
    u16* XhT = (u16*)p;  p += (size_t)BB * 256 * 1024 * 2;
    u16* HnT = (u16*)p;  p += (size_t)BB * 256 * 1024 * 2;
    u16* OnT = (u16*)p;  p += (size_t)BB * 256 * 1024 * 2;
    u16* Whf = (u16*)p;  p += (size_t)2 * 256 * K1 * 2;
    u16* Whm = (u16*)p;  p += (size_t)6 * 4 * 256 * 256 * 2;
    u16* Whl = (u16*)p;  p += (size_t)2 * 256 * 256 * 2;

    k_ftrans<<<dim3(128, 16), 256, 0, stream>>>(features, featT);
    k_interp<<<BN / 4, 256, 0, stream>>>(featT, base_point, Xh);
    k_xt<<<dim3(8, 16), 256, 0, stream>>>(Xh, XhT);

    k_cast4<<<2048, 256, 0, stream>>>(adj, adjh, (long)BB * NN * NN / 4);
    k_cast4<<<256, 256, 0, stream>>>(mid_W, Whm, (long)6 * 4 * 256 * 256 / 4);
    k_cast4<<<64, 256, 0, stream>>>(last_W, Whl, (long)2 * 256 * 256 / 4);
    k_castW1<<<(2 * 256 * K1 + 255) / 256, 256, 0, stream>>>(first_W, Whf);

    const long sA = (long)NN * NN, sB = 256L * 1024, sC = (long)NN * 256;
    dim3 gAgg(2, 8, 16), gGc(2, 128, 1), blk(512);

    // first layer
    k_mm<<<gAgg, blk, 0, stream>>>(adjh, NN, 16, nullptr, 0, 0, XhT, NN, nullptr, 0,
                                   nullptr, nullptr, nullptr, 0,
                                   AGG, 256, nullptr, 1, sA, sB, sC);
    k_mm<<<gGc, blk, 0, stream>>>(Xh, K1, 3, AGG, 256, 3, Whf, K1, Whf + 256 * K1, K1,
                                  first_b, first_b + 256, nullptr, 1,
                                  Hn, 256, HnT, 0, 0, 0, 0);

    for (int i = 0; i < 6; ++i) {
        const u16* W = Whm + (size_t)i * 4 * 256 * 256;
        const float* bb = mid_b + (size_t)i * 4 * 256;
        k_mm<<<gAgg, blk, 0, stream>>>(adjh, NN, 16, nullptr, 0, 0, HnT, NN, nullptr, 0,
                                       nullptr, nullptr, nullptr, 0,
                                       AGG, 256, nullptr, 1, sA, sB, sC);
        k_mm<<<gGc, blk, 0, stream>>>(Hn, 256, 4, AGG, 256, 4, W, 256, W + 65536, 256,
                                      bb, bb + 256, nullptr, 1,
                                      On, 256, OnT, 0, 0, 0, 0);
        k_mm<<<gAgg, blk, 0, stream>>>(adjh, NN, 16, nullptr, 0, 0, OnT, NN, nullptr, 0,
                                       nullptr, nullptr, nullptr, 0,
                                       AGG, 256, nullptr, 1, sA, sB, sC);
        k_mm<<<gGc, blk, 0, stream>>>(On, 256, 4, AGG, 256, 4,
                                      W + 2 * 65536, 256, W + 3 * 65536, 256,
                                      bb + 512, bb + 768, Hn, 1,
                                      Hn, 256, HnT, 0, 0, 0, 0);
    }

    // last layer
    k_mm<<<gAgg, blk, 0, stream>>>(adjh, NN, 16, nullptr, 0, 0, HnT, NN, nullptr, 0,
                                   nullptr, nullptr, nullptr, 0,
                                   AGG, 256, nullptr, 1, sA, sB, sC);
    k_mm<<<gGc, blk, 0, stream>>>(Hn, 256, 4, AGG, 256, 4, Whl, 256, Whl + 65536, 256,
                                  last_b, last_b + 256, nullptr, 1,
                                  On, 256, nullptr, 0, 0, 0, 0);

    // head + energy
    k_fc<<<BN / 32, 256, 0, stream>>>(On, fc_W, fc_b, base_point, mask, out, G);
    k_adjg<<<BN / 4, 256, 0, stream>>>(adjh, G, AG);
    k_energy<<<BB, 256, 0, stream>>>(G, AG, out);
}

// Round 8
// 598.786 us; speedup vs baseline: 1.3135x; 1.1704x over previous
//
#include <hip/hip_runtime.h>
#include <cmath>

#define BB 16
#define CC 128
#define HH 128
#define WW 128
#define NN 1024
#define SS 256
#define BN (BB*NN)
#define K1 192            // first-layer K padded: 130 -> 192 (3 x 64)

typedef short short8v __attribute__((ext_vector_type(8)));
typedef float f32x4 __attribute__((ext_vector_type(4)));
typedef unsigned short u16;

__device__ __forceinline__ u16 f2bf(float f) {
    unsigned u = __builtin_bit_cast(unsigned, f);
    unsigned r = (u + 0x7FFFu + ((u >> 16) & 1u)) >> 16;
    return (u16)r;
}
__device__ __forceinline__ float bf2f(u16 h) {
    unsigned u = ((unsigned)h) << 16;
    return __builtin_bit_cast(float, u);
}

// ---------------------------------------------------------------------------
// casts
// ---------------------------------------------------------------------------
__global__ void k_cast4(const float* __restrict__ s, u16* __restrict__ d, long n4) {
    long i = (long)blockIdx.x * blockDim.x + threadIdx.x;
    long st = (long)gridDim.x * blockDim.x;
    for (; i < n4; i += st) {
        float4 v = ((const float4*)s)[i];
        ushort4 o;
        o.x = f2bf(v.x); o.y = f2bf(v.y); o.z = f2bf(v.z); o.w = f2bf(v.w);
        ((ushort4*)d)[i] = o;
    }
}

// first_W [2][256][130] -> bf16 [2][256][192] zero-padded
__global__ void k_castW1(const float* __restrict__ s, u16* __restrict__ d) {
    int idx = blockIdx.x * blockDim.x + threadIdx.x;
    if (idx >= 2 * 256 * K1) return;
    int k = idx % K1, r = idx / K1;
    d[idx] = (k < 130) ? f2bf(s[r * 130 + k]) : (u16)0;
}

// ---------------------------------------------------------------------------
// features [16][128][16384] f32 -> featT [16][16384][128] bf16 (tiled transpose)
// ---------------------------------------------------------------------------
__global__ __launch_bounds__(256) void k_ftrans(const float* __restrict__ f,
                                                u16* __restrict__ ft) {
    __shared__ u16 T[128][132];
    int b = blockIdx.y, hw0 = blockIdx.x * 128;
    int t = threadIdx.x;
    const float* fb = f + (long)b * CC * (HH * WW);
    #pragma unroll
    for (int p = 0; p < 16; ++p) {
        int c = p * 8 + (t >> 5);
        int x = (t & 31) * 4;
        float4 v = *(const float4*)(fb + (long)c * (HH * WW) + hw0 + x);
        T[x + 0][c] = f2bf(v.x); T[x + 1][c] = f2bf(v.y);
        T[x + 2][c] = f2bf(v.z); T[x + 3][c] = f2bf(v.w);
    }
    __syncthreads();
    #pragma unroll
    for (int p = 0; p < 8; ++p) {
        int hw = p * 16 + (t >> 4);
        int c8 = (t & 15) * 8;
        short8v v = *(const short8v*)&T[hw][c8];
        *(short8v*)(ft + ((long)b * 16384 + hw0 + hw) * 128 + c8) = v;
    }
}

// ---------------------------------------------------------------------------
// interp: wave per node; lane = (corner<<4)|chunk.
// ---------------------------------------------------------------------------
__global__ __launch_bounds__(256) void k_interp(const u16* __restrict__ featT,
                                                const float* __restrict__ base_point,
                                                u16* __restrict__ Xh) {
    int t = threadIdx.x;
    int lane = t & 63, w = t >> 6;
    int bn = blockIdx.x * 4 + w;
    int b = bn >> 10;
    float px = base_point[bn * 2 + 0];
    float py = base_point[bn * 2 + 1];
    float Xs = px * WW, Ys = py * HH;
    float X0f = floorf(Xs), Y0f = floorf(Ys);
    float fx = Xs - X0f, fy = Ys - Y0f;
    int x0 = min(max((int)X0f, 0), WW - 1);
    int x1 = min(max((int)(X0f + 1.f), 0), WW - 1);
    int y0 = min(max((int)Y0f, 0), HH - 1);
    int y1 = min(max((int)(Y0f + 1.f), 0), HH - 1);
    int corner = lane >> 4, chunk = lane & 15;
    int xi = (corner & 2) ? x1 : x0;
    int yi = (corner & 1) ? y1 : y0;
    float wgt = ((corner & 2) ? fx : 1.f - fx) * ((corner & 1) ? fy : 1.f - fy);
    const u16* fp = featT + ((long)b * 16384 + yi * WW + xi) * 128 + chunk * 8;
    short8v v = *(const short8v*)fp;
    float a[8];
    #pragma unroll
    for (int j = 0; j < 8; ++j) a[j] = wgt * bf2f((u16)v[j]);
    #pragma unroll
    for (int j = 0; j < 8; ++j) {
        a[j] += __shfl_xor(a[j], 16);
        a[j] += __shfl_xor(a[j], 32);
    }
    if (lane < 16) {
        short8v o;
        #pragma unroll
        for (int j = 0; j < 8; ++j) o[j] = (short)f2bf(a[j]);
        *(short8v*)(Xh + (long)bn * K1 + chunk * 8) = o;
    } else if (lane < 24) {
        short8v o = {};
        if (lane == 16) { o[0] = (short)f2bf(px); o[1] = (short)f2bf(py); }
        *(short8v*)(Xh + (long)bn * K1 + 128 + (lane - 16) * 8) = o;
    }
}

// ---------------------------------------------------------------------------
// Xh [16384][192] -> XhT [16][256][1024], rows 192..255 zeroed
// ---------------------------------------------------------------------------
__global__ __launch_bounds__(256) void k_xt(const u16* __restrict__ Xh,
                                            u16* __restrict__ XhT) {
    __shared__ u16 T[192][136];
    int b = blockIdx.y, n0 = blockIdx.x * 128;
    int t = threadIdx.x;
    #pragma unroll
    for (int p = 0; p < 12; ++p) {
        int idx = p * 256 + t;
        int node = idx / 24, ch = idx % 24;
        short8v v = *(const short8v*)(Xh + ((long)(b * 1024 + n0 + node)) * K1 + ch * 8);
        #pragma unroll
        for (int j = 0; j < 8; ++j) T[ch * 8 + j][node] = (u16)v[j];
    }
    __syncthreads();
    #pragma unroll
    for (int p = 0; p < 12; ++p) {
        int c = p * 16 + (t >> 4);
        int m8 = (t & 15) * 8;
        short8v v = *(const short8v*)&T[c][m8];
        *(short8v*)(XhT + ((long)b * 256 + c) * 1024 + n0 + m8) = v;
    }
    #pragma unroll
    for (int p = 0; p < 4; ++p) {
        int c = 192 + p * 16 + (t >> 4);
        int m8 = (t & 15) * 8;
        short8v z = {};
        *(short8v*)(XhT + ((long)b * 256 + c) * 1024 + n0 + m8) = z;
    }
}

// ---------------------------------------------------------------------------
// MFMA GEMM, 8 waves, 128x128 tile, BK=64.
// 3-stage LDS pipeline (96 KB), 2-deep prefetch, counted vmcnt, 1 barrier/step.
// PAIR-SWIZZLE: the two col-blocks (bx=0/1) sharing one A-slice map to HW
// blocks h and h+8 -> same XCD -> second A-read hits that XCD's L2.
// C = [A0|A1] @ [B0|B1]^T (+bias +res, relu). B stored [n][K] k-contig.
// ---------------------------------------------------------------------------
__global__ __launch_bounds__(512) void k_mm(
    const u16* __restrict__ A0, int lda0, int nK0,
    const u16* __restrict__ A1, int lda1, int nK1,
    const u16* __restrict__ B0, int ldb0,
    const u16* __restrict__ B1, int ldb1,
    const float* __restrict__ bias0, const float* __restrict__ bias1,
    const u16* __restrict__ res, int do_relu,
    u16* __restrict__ outN, int ldoN,
    u16* __restrict__ outT,
    int batched, long sA, long sB, long sC) {

    __shared__ u16 lds[49152];               // 96 KB: 3 x (As 16KB + Bs 16KB)

    int t = threadIdx.x;
    int lane = t & 63, w = t >> 6;           // 8 waves
    int wr = w >> 1, wc = w & 1;             // 4x2 waves of 32x64

    // pair-swizzle (bijective, grids are (2,8,16) or (2,128,1) = 256 blocks)
    int bx, by, bz;
    {
        int gy = batched ? 8 : 128;
        int h = blockIdx.x + 2 * (blockIdx.y + gy * blockIdx.z);
        bx = (h >> 3) & 1;
        int p = (h & 7) | ((h >> 4) << 3);
        if (batched) { by = p & 7; bz = p >> 3; }
        else         { by = p;     bz = 0;      }
    }
    int c0 = bx * 128;
    long row0 = (long)by * 128;
    const u16* Ab0 = A0;
    const u16* Bb0 = B0;
    u16* oN = outN;
    if (batched) {
        Ab0 += (long)bz * sA;
        Bb0 += (long)bz * sB;
        oN  += (long)bz * sC;
    }

    int tot = nK0 + nK1;
    f32x4 acc[2][4] = {};

    auto stage = [&](int s, int bufbase) {   // issues 4 global_load_lds
        const u16* Ap; int lda; const u16* Bp; int ldb; int kt;
        if (s < nK0) { Ap = Ab0; lda = lda0; Bp = Bb0; ldb = ldb0; kt = s * 64; }
        else         { Ap = A1;  lda = lda1; Bp = B1;  ldb = ldb1; kt = (s - nK0) * 64; }
        u16* As = lds + bufbase;
        u16* Bs = lds + bufbase + 8192;
        #pragma unroll
        for (int q = 0; q < 2; ++q) {
            int rb = w * 16 + q * 8;
            int row = rb + (lane >> 3);
            int koff = kt + (((lane & 7) ^ (row & 7)) << 3);
            __builtin_amdgcn_global_load_lds(
                (const __attribute__((address_space(1))) void*)(Ap + (row0 + row) * lda + koff),
                (__attribute__((address_space(3))) void*)(As + rb * 64), 16, 0, 0);
            __builtin_amdgcn_global_load_lds(
                (const __attribute__((address_space(1))) void*)(Bp + (long)(c0 + row) * ldb + koff),
                (__attribute__((address_space(3))) void*)(Bs + rb * 64), 16, 0, 0);
        }
    };

    stage(0, 0);
    if (tot > 1) stage(1, 16384);

    int curb = 0, stb = 32768;
    for (int s = 0; s < tot; ++s) {
        if (s + 1 < tot) { asm volatile("s_waitcnt vmcnt(4)" ::: "memory"); }
        else             { asm volatile("s_waitcnt vmcnt(0)" ::: "memory"); }
        __builtin_amdgcn_sched_barrier(0);
        __builtin_amdgcn_s_barrier();        // buffer landed + prev reads done
        if (s + 2 < tot) stage(s + 2, stb);  // overwrites buffer read 1 iter ago
        const u16* As = lds + curb;
        const u16* Bs = lds + curb + 8192;
        #pragma unroll
        for (int kk = 0; kk < 2; ++kk) {
            short8v a[2], bfr[4];
            #pragma unroll
            for (int m = 0; m < 2; ++m) {
                int row = wr * 32 + m * 16 + (lane & 15);
                int sl = (kk * 4 + (lane >> 4)) ^ (row & 7);
                a[m] = *(const short8v*)(As + row * 64 + sl * 8);
            }
            #pragma unroll
            for (int n = 0; n < 4; ++n) {
                int row = wc * 64 + n * 16 + (lane & 15);
                int sl = (kk * 4 + (lane >> 4)) ^ (row & 7);
                bfr[n] = *(const short8v*)(Bs + row * 64 + sl * 8);
            }
            #pragma unroll
            for (int m = 0; m < 2; ++m)
                #pragma unroll
                for (int n = 0; n < 4; ++n)
                    acc[m][n] = __builtin_amdgcn_mfma_f32_16x16x32_bf16(
                        a[m], bfr[n], acc[m][n], 0, 0, 0);
        }
        curb += 16384; if (curb == 49152) curb = 0;
        stb  += 16384; if (stb  == 49152) stb  = 0;
    }

    // ---- epilogue ----
    int mbase = wr * 32, nbase = wc * 64;
    u16 vals[2][4][4];
    #pragma unroll
    for (int m = 0; m < 2; ++m)
        #pragma unroll
        for (int n = 0; n < 4; ++n)
            #pragma unroll
            for (int r = 0; r < 4; ++r) {
                int rr = mbase + m * 16 + (lane >> 4) * 4 + r;
                int cc = nbase + n * 16 + (lane & 15);
                long grow = row0 + rr;
                int gcol = c0 + cc;
                float v = acc[m][n][r];
                if (bias0) v += bias0[gcol] + bias1[gcol];
                if (res)   v += bf2f(res[grow * ldoN + gcol]);
                if (do_relu) v = fmaxf(v, 0.f);
                u16 hv = f2bf(v);
                oN[grow * ldoN + gcol] = hv;
                vals[m][n][r] = hv;
            }

    if (outT) {
        u16 (*T)[136] = (u16(*)[136])lds;     // 128 x 136 = 34.8 KB
        __syncthreads();
        #pragma unroll
        for (int m = 0; m < 2; ++m)
            #pragma unroll
            for (int n = 0; n < 4; ++n)
                #pragma unroll
                for (int r = 0; r < 4; ++r) {
                    int rr = mbase + m * 16 + (lane >> 4) * 4 + r;
                    int cc = nbase + n * 16 + (lane & 15);
                    T[cc][rr] = vals[m][n][r];
                }
        __syncthreads();
        int bb2 = (int)(row0 >> 10);
        long nodeBase = row0 & 1023;
        #pragma unroll
        for (int p = 0; p < 4; ++p) {
            int c = p * 32 + (t >> 4);
            int moff = (t & 15) * 8;
            short8v vv = *(const short8v*)(&T[c][moff]);
            *(short8v*)(outT + ((long)bb2 * 256 + c0 + c) * 1024 + nodeBase + moff) = vv;
        }
    }
}

// ---------------------------------------------------------------------------
// FC head: 8 lanes per node, shfl reduce. grid 512 x 256.
// ---------------------------------------------------------------------------
__global__ __launch_bounds__(256) void k_fc(const u16* __restrict__ Hf,
                     const float* __restrict__ fcW, const float* __restrict__ fcb,
                     const float* __restrict__ base_point,
                     const float* __restrict__ mask,
                     float* __restrict__ out, float* __restrict__ G) {
    int t = threadIdx.x;
    int w = t >> 6, l = t & 63;
    int bn = blockIdx.x * 32 + w * 8 + (l >> 3);
    int kc = (l & 7) * 32;
    const u16* hr = Hf + (long)bn * SS + kc;
    float a0 = 0.f, a1 = 0.f;
    #pragma unroll
    for (int j = 0; j < 32; j += 8) {
        short8v v = *(const short8v*)(hr + j);
        #pragma unroll
        for (int jj = 0; jj < 8; ++jj) {
            float f = bf2f((u16)v[jj]);
            a0 += f * fcW[kc + j + jj];
            a1 += f * fcW[SS + kc + j + jj];
        }
    }
    #pragma unroll
    for (int off = 1; off < 8; off <<= 1) {
        a0 += __shfl_xor(a0, off);
        a1 += __shfl_xor(a1, off);
    }
    if ((l & 7) == 0) {
        a0 += fcb[0]; a1 += fcb[1];
        float m  = mask[bn];
        float p0 = base_point[bn * 2 + 0], p1 = base_point[bn * 2 + 1];
        float g0 = a0 * m, g1 = a1 * m;
        out[16 + bn * 2 + 0] = p0 + g0;
        out[16 + bn * 2 + 1] = p1 + g1;
        out[16 + BN * 2 + bn * 2 + 0] = a0;
        out[16 + BN * 2 + bn * 2 + 1] = a1;
        G[bn * 2 + 0] = g0;
        G[bn * 2 + 1] = g1;
    }
}

// ---------------------------------------------------------------------------
// AG = adj @ G (fp32 G, bf16 adj); one wave per output row
// ---------------------------------------------------------------------------
__global__ __launch_bounds__(256) void k_adjg(const u16* __restrict__ adjh,
                                              const float* __restrict__ G,
                                              float* __restrict__ AG) {
    int w = threadIdx.x >> 6, lane = threadIdx.x & 63;
    long row = (long)blockIdx.x * 4 + w;
    int b = (int)(row >> 10);
    const u16* ar = adjh + ((long)b * NN + (row & 1023)) * NN;
    const float* Gb = G + (long)b * NN * 2;
    float s0 = 0.f, s1 = 0.f;
    int k0 = lane * 16;
    #pragma unroll
    for (int q = 0; q < 2; ++q) {
        short8v av = *(const short8v*)(ar + k0 + q * 8);
        #pragma unroll
        for (int j = 0; j < 8; ++j) {
            float a = bf2f((u16)av[j]);
            int k = k0 + q * 8 + j;
            s0 += a * Gb[k * 2 + 0];
            s1 += a * Gb[k * 2 + 1];
        }
    }
    #pragma unroll
    for (int off = 32; off; off >>= 1) {
        s0 += __shfl_down(s0, off);
        s1 += __shfl_down(s1, off);
    }
    if (lane == 0) { AG[row * 2 + 0] = s0; AG[row * 2 + 1] = s1; }
}

// ---------------------------------------------------------------------------
// energy
// ---------------------------------------------------------------------------
__global__ __launch_bounds__(256) void k_energy(const float* __restrict__ G,
                                                const float* __restrict__ AG,
                                                float* __restrict__ out) {
    __shared__ float red[256];
    int b = blockIdx.x, t = threadIdx.x;
    float s = 0.f;
    for (int n = t; n < NN; n += 256) {
        int bn = b * NN + n;
        float dx = G[bn * 2 + 0] - AG[bn * 2 + 0];
        float dy = G[bn * 2 + 1] - AG[bn * 2 + 1];
        s += sqrtf(dx * dx + dy * dy + 1e-10f);
    }
    red[t] = s;
    __syncthreads();
    for (int off = 128; off > 0; off >>= 1) {
        if (t < off) red[t] += red[t + off];
        __syncthreads();
    }
    if (t == 0) out[b] = red[0] / (float)NN;
}

// ---------------------------------------------------------------------------
extern "C" void kernel_launch(void* const* d_in, const int* in_sizes, int n_in,
                              void* d_out, int out_size, void* d_ws, size_t ws_size,
                              hipStream_t stream) {
    const float* features   = (const float*)d_in[0];
    const float* base_point = (const float*)d_in[1];
    const float* adj        = (const float*)d_in[2];
    const float* mask       = (const float*)d_in[3];
    const float* first_W    = (const float*)d_in[4];
    const float* first_b    = (const float*)d_in[5];
    const float* mid_W      = (const float*)d_in[6];
    const float* mid_b      = (const float*)d_in[7];
    const float* last_W     = (const float*)d_in[8];
    const float* last_b     = (const float*)d_in[9];
    const float* fc_W       = (const float*)d_in[10];
    const float* fc_b       = (const float*)d_in[11];
    float* out = (float*)d_out;
    char* p = (char*)d_ws;

    // Region 0 (67.1 MB): featT first; then reused for adjh / AGG / Hn / On / G / AG.
    u16*  featT = (u16*)p;
    u16*  adjh  = (u16*)p;                                   // 33.55 MB
    u16*  AGG   = (u16*)(p + 33554432);                      //  8.39 MB
    u16*  Hn    = (u16*)(p + 33554432 + 8388608);            //  8.39 MB
    u16*  On    = (u16*)(p + 33554432 + 2 * 8388608);        //  8.39 MB
    float* G    = (float*)(p + 33554432 + 3 * 8388608);      //  0.13 MB
    float* AG   = G + (size_t)BN * 2;                        //  0.13 MB
    p += (size_t)BB * 16384 * 128 * 2;                       // 67108864

    u16* Xh  = (u16*)p;  p += (size_t)BN * K1 * 2;
    u16* XhT = (u16*)p;  p += (size_t)BB * 256 * 1024 * 2;
    u16* HnT = (u16*)p;  p += (size_t)BB * 256 * 1024 * 2;
    u16* OnT = (u16*)p;  p += (size_t)BB * 256 * 1024 * 2;
    u16* Whf = (u16*)p;  p += (size_t)2 * 256 * K1 * 2;
    u16* Whm = (u16*)p;  p += (size_t)6 * 4 * 256 * 256 * 2;
    u16* Whl = (u16*)p;  p += (size_t)2 * 256 * 256 * 2;

    k_ftrans<<<dim3(128, 16), 256, 0, stream>>>(features, featT);
    k_interp<<<BN / 4, 256, 0, stream>>>(featT, base_point, Xh);
    k_xt<<<dim3(8, 16), 256, 0, stream>>>(Xh, XhT);

    k_cast4<<<2048, 256, 0, stream>>>(adj, adjh, (long)BB * NN * NN / 4);
    k_cast4<<<256, 256, 0, stream>>>(mid_W, Whm, (long)6 * 4 * 256 * 256 / 4);
    k_cast4<<<64, 256, 0, stream>>>(last_W, Whl, (long)2 * 256 * 256 / 4);
    k_castW1<<<(2 * 256 * K1 + 255) / 256, 256, 0, stream>>>(first_W, Whf);

    const long sA = (long)NN * NN, sB = 256L * 1024, sC = (long)NN * 256;
    dim3 gAgg(2, 8, 16), gGc(2, 128, 1), blk(512);

    // first layer
    k_mm<<<gAgg, blk, 0, stream>>>(adjh, NN, 16, nullptr, 0, 0, XhT, NN, nullptr, 0,
                                   nullptr, nullptr, nullptr, 0,
                                   AGG, 256, nullptr, 1, sA, sB, sC);
    k_mm<<<gGc, blk, 0, stream>>>(Xh, K1, 3, AGG, 256, 3, Whf, K1, Whf + 256 * K1, K1,
                                  first_b, first_b + 256, nullptr, 1,
                                  Hn, 256, HnT, 0, 0, 0, 0);

    for (int i = 0; i < 6; ++i) {
        const u16* W = Whm + (size_t)i * 4 * 256 * 256;
        const float* bb = mid_b + (size_t)i * 4 * 256;
        k_mm<<<gAgg, blk, 0, stream>>>(adjh, NN, 16, nullptr, 0, 0, HnT, NN, nullptr, 0,
                                       nullptr, nullptr, nullptr, 0,
                                       AGG, 256, nullptr, 1, sA, sB, sC);
        k_mm<<<gGc, blk, 0, stream>>>(Hn, 256, 4, AGG, 256, 4, W, 256, W + 65536, 256,
                                      bb, bb + 256, nullptr, 1,
                                      On, 256, OnT, 0, 0, 0, 0);
        k_mm<<<gAgg, blk, 0, stream>>>(adjh, NN, 16, nullptr, 0, 0, OnT, NN, nullptr, 0,
                                       nullptr, nullptr, nullptr, 0,
                                       AGG, 256, nullptr, 1, sA, sB, sC);
        k_mm<<<gGc, blk, 0, stream>>>(On, 256, 4, AGG, 256, 4,
                                      W + 2 * 65536, 256, W + 3 * 65536, 256,
                                      bb + 512, bb + 768, Hn, 1,
                                      Hn, 256, HnT, 0, 0, 0, 0);
    }

    // last layer
    k_mm<<<gAgg, blk, 0, stream>>>(adjh, NN, 16, nullptr, 0, 0, HnT, NN, nullptr, 0,
                                   nullptr, nullptr, nullptr, 0,
                                   AGG, 256, nullptr, 1, sA, sB, sC);
    k_mm<<<gGc, blk, 0, stream>>>(Hn, 256, 4, AGG, 256, 4, Whl, 256, Whl + 65536, 256,
                                  last_b, last_b + 256, nullptr, 1,
                                  On, 256, nullptr, 0, 0, 0, 0);

    // head + energy
    k_fc<<<BN / 32, 256, 0, stream>>>(On, fc_W, fc_b, base_point, mask, out, G);
    k_adjg<<<BN / 4, 256, 0, stream>>>(adjh, G, AG);
    k_energy<<<BB, 256, 0, stream>>>(G, AG, out);
}